// Round 1
// baseline (3001.015 us; speedup 1.0000x reference)
//
#include <hip/hip_runtime.h>

#define N 256
#define NT 256
#define LAM 0.05f      // step = ALPHA/2 = 0.1/2
#define MAXIT 35
#define TOL 0.01f

// v(k) = a[k*str] + b[k*str]
__device__ __forceinline__ float ld2(const float* a, const float* b, int k, int str) {
    return a[k * str] + b[k * str];
}

// Condat's direct 1D total-variation prox (exact, O(1) extra state).
// Reads v(k)=a[k*str]+b[k*str], writes out[k*ostr], length N.
__device__ void tv1d_condat(const float* __restrict__ a, const float* __restrict__ b,
                            float* __restrict__ out, const int str, const int ostr)
{
    const int width = N;
    int k = 0, k0 = 0, kminus = 0, kplus = 0;
    const float lam = LAM, mlam = -LAM, twolam = 2.0f * LAM;
    float umin = lam, umax = mlam;
    float v0 = a[0] + b[0];
    float vmin = v0 - lam, vmax = v0 + lam;
    int guard = 0;
    for (;;) {
        if (++guard > 400000) return;  // safety: algorithm provably terminates, belt+suspenders
        while (k == width - 1) {
            if (umin < 0.0f) {            // negative jump at right boundary
                do { out[k0 * ostr] = vmin; k0++; } while (k0 <= kminus);
                if (k0 > width - 1) return;
                kminus = k = k0;
                vmin = ld2(a, b, k0, str);
                umin = lam;
                umax = vmin + lam - vmax;
            } else if (umax > 0.0f) {     // positive jump at right boundary
                do { out[k0 * ostr] = vmax; k0++; } while (k0 <= kplus);
                if (k0 > width - 1) return;
                kplus = k = k0;
                vmax = ld2(a, b, k0, str);
                umax = mlam;
                umin = vmax - lam - vmin;
            } else {                      // done: flush last segment
                vmin += umin / (float)(k - k0 + 1);
                do { out[k0 * ostr] = vmin; k0++; } while (k0 <= k);
                return;
            }
        }
        float vn = ld2(a, b, k + 1, str);
        umin += vn - vmin;
        if (umin < mlam) {               // negative jump
            do { out[k0 * ostr] = vmin; k0++; } while (k0 <= kminus);
            kplus = kminus = k = k0;
            vmin = ld2(a, b, k0, str);
            vmax = vmin + twolam;
            umin = lam; umax = mlam;
        } else {
            umax += vn - vmax;
            if (umax > lam) {            // positive jump
                do { out[k0 * ostr] = vmax; k0++; } while (k0 <= kplus);
                kplus = kminus = k = k0;
                vmax = ld2(a, b, k0, str);
                vmin = vmax - twolam;
                umin = lam; umax = mlam;
            } else {                     // no jump
                k++;
                if (umin >= lam) { vmin += (umin - lam) / (float)(k - k0 + 1); umin = lam; kminus = k; }
                if (umax <= mlam) { vmax += (umax + lam) / (float)(k - k0 + 1); umax = mlam; kplus = k; }
            }
        }
    }
}

// Single-block Douglas-Rachford TV2D. thread t owns column t (phase 1) and row t (phase 2).
__global__ __launch_bounds__(NT) void tv2d_kernel(const float* __restrict__ X,
                                                  float* __restrict__ xw,  // = d_out
                                                  float* __restrict__ p,
                                                  float* __restrict__ q,
                                                  float* __restrict__ y)
{
    const int t = threadIdx.x;
    __shared__ float red[NT];
    __shared__ int conv;

    // init: x = X, p = q = 0 (ws is poisoned each call)
    for (int i = t; i < N * N; i += NT) {
        xw[i] = X[i];
        p[i]  = 0.0f;
        q[i]  = 0.0f;
    }
    __syncthreads();

    for (int it = 0; it < MAXIT; ++it) {
        // ---- column phase: y = prox_cols(x + p); p += x - y ----
        tv1d_condat(xw + t, p + t, y + t, N, N);
        for (int k = 0; k < N; ++k) {
            const int idx = k * N + t;
            p[idx] += xw[idx] - y[idx];
        }
        __syncthreads();

        // ---- row phase: x2 = prox_rows(y + q); q += y - x2; acc = max|y - x2| ----
        tv1d_condat(y + t * N, q + t * N, xw + t * N, 1, 1);
        float am = 0.0f;
        for (int k = 0; k < N; ++k) {
            const int idx = t * N + k;
            const float d = y[idx] - xw[idx];
            q[idx] += d;
            am = fmaxf(am, fabsf(d));
        }
        red[t] = am;
        __syncthreads();
        for (int s = NT / 2; s > 0; s >>= 1) {
            if (t < s) red[t] = fmaxf(red[t], red[t + s]);
            __syncthreads();
        }
        if (t == 0) conv = (red[0] < TOL) ? 1 : 0;
        __syncthreads();
        if (conv) break;   // matches reference while_loop: stop when acc < tol
    }
    // xw (= d_out) holds the final x2
}

extern "C" void kernel_launch(void* const* d_in, const int* in_sizes, int n_in,
                              void* d_out, int out_size, void* d_ws, size_t ws_size,
                              hipStream_t stream) {
    const float* X = (const float*)d_in[0];
    float* xw = (float*)d_out;
    float* ws = (float*)d_ws;
    float* p = ws;
    float* q = ws + N * N;
    float* y = ws + 2 * N * N;
    tv2d_kernel<<<1, NT, 0, stream>>>(X, xw, p, q, y);
}

// Round 2
// 1171.581 us; speedup vs baseline: 2.5615x; 2.5615x over previous
//
#include <hip/hip_runtime.h>
#include <hip/hip_cooperative_groups.h>

#define N 256
#define NLINE 4               // lines (waves) per block
#define NB (N / NLINE)        // 64 blocks
#define NT (NLINE * 64)       // 256 threads
#define LAM 0.05f             // step = ALPHA/2
#define MAXIT 35
#define TOL 0.01f

namespace cg = cooperative_groups;

// broadcast-read one lane's register (k uniform -> v_readlane, result in SGPR)
__device__ __forceinline__ float rlane(float v, int lane) {
    return __int_as_float(__builtin_amdgcn_readlane(__float_as_int(v), lane));
}

// a 256-float line distributed over the wave: element k lives in lane (k&63), reg (k>>6)
struct Dist { float r0, r1, r2, r3; };

__device__ __forceinline__ float dfetch(const Dist& d, int k, int lane_self) {
    (void)lane_self;
    const int lane = k & 63;
    switch (k >> 6) {            // uniform branch -> only waits on the needed reg
        case 0:  return rlane(d.r0, lane);
        case 1:  return rlane(d.r1, lane);
        case 2:  return rlane(d.r2, lane);
        default: return rlane(d.r3, lane);
    }
}

__device__ __forceinline__ void dstore(Dist& d, int k, float val, int lane_self) {
    const bool mine = (lane_self == (k & 63));
    switch (k >> 6) {            // uniform branch; cndmask on the owning lane only
        case 0:  d.r0 = mine ? val : d.r0; break;
        case 1:  d.r1 = mine ? val : d.r1; break;
        case 2:  d.r2 = mine ? val : d.r2; break;
        default: d.r3 = mine ? val : d.r3; break;
    }
}

// Condat's exact 1D TV prox, wave-uniform control flow, register-resident line.
__device__ void tv1d_scan(const Dist& v, Dist& o, const int lane)
{
    int k = 0, k0 = 0, km = 0, kp = 0;
    const float lam = LAM, mlam = -LAM, twolam = 2.0f * LAM;
    float umin = lam, umax = mlam;
    float v0 = rlane(v.r0, 0);
    float vmin = v0 - lam, vmax = v0 + lam;
    int guard = 0;
    for (;;) {
        if (++guard > 100000) return;   // provably terminates; belt+suspenders
        while (k == N - 1) {
            if (umin < 0.0f) {
                do { dstore(o, k0, vmin, lane); k0++; } while (k0 <= km);
                if (k0 > N - 1) return;
                km = k = k0;
                vmin = dfetch(v, k0, lane);
                umin = lam;
                umax = vmin + lam - vmax;
            } else if (umax > 0.0f) {
                do { dstore(o, k0, vmax, lane); k0++; } while (k0 <= kp);
                if (k0 > N - 1) return;
                kp = k = k0;
                vmax = dfetch(v, k0, lane);
                umax = mlam;
                umin = vmax - lam - vmin;
            } else {
                vmin += umin / (float)(k - k0 + 1);
                do { dstore(o, k0, vmin, lane); k0++; } while (k0 <= k);
                return;
            }
        }
        float vn = dfetch(v, k + 1, lane);
        umin += vn - vmin;
        if (umin < mlam) {                      // negative jump
            do { dstore(o, k0, vmin, lane); k0++; } while (k0 <= km);
            kp = km = k = k0;
            vmin = dfetch(v, k0, lane);
            vmax = vmin + twolam;
            umin = lam; umax = mlam;
        } else {
            umax += vn - vmax;
            if (umax > lam) {                   // positive jump
                do { dstore(o, k0, vmax, lane); k0++; } while (k0 <= kp);
                kp = km = k = k0;
                vmax = dfetch(v, k0, lane);
                vmin = vmax - twolam;
                umin = lam; umax = mlam;
            } else {                            // no jump
                k++;
                if (umin >= lam)  { vmin += (umin - lam) / (float)(k - k0 + 1); umin = lam;  km = k; }
                if (umax <= mlam) { vmax += (umax + lam) / (float)(k - k0 + 1); umax = mlam; kp = k; }
            }
        }
    }
}

// Douglas-Rachford TV2D: wave w of block b owns column (4b+w) in phase 1 and row (4b+w)
// in phase 2. p (column-local) and q (row-local) persist in registers across iterations.
__global__ __launch_bounds__(NT) void tv2d_coop(const float* __restrict__ X,
                                                float* __restrict__ xw,   // = d_out, holds x
                                                float* __restrict__ y,
                                                unsigned* __restrict__ acc)
{
    cg::grid_group grid = cg::this_grid();
    const int t = threadIdx.x;
    const int lane = t & 63;
    const int wave = t >> 6;
    const int line = blockIdx.x * NLINE + wave;

    if (blockIdx.x == 0 && t < MAXIT) acc[t] = 0u;   // ordered before use by first grid.sync

    Dist p = {0.f, 0.f, 0.f, 0.f};
    Dist q = {0.f, 0.f, 0.f, 0.f};

    for (int it = 0; it < MAXIT; ++it) {
        // ---- column phase: y = prox(x + p) on column `line`; p = v - y ----
        const float* xs = (it == 0) ? X : xw;
        Dist v, o = {0.f, 0.f, 0.f, 0.f};
        v.r0 = xs[(lane      ) * N + line] + p.r0;
        v.r1 = xs[(lane +  64) * N + line] + p.r1;
        v.r2 = xs[(lane + 128) * N + line] + p.r2;
        v.r3 = xs[(lane + 192) * N + line] + p.r3;
        tv1d_scan(v, o, lane);
        p.r0 = v.r0 - o.r0;  p.r1 = v.r1 - o.r1;
        p.r2 = v.r2 - o.r2;  p.r3 = v.r3 - o.r3;
        y[(lane      ) * N + line] = o.r0;
        y[(lane +  64) * N + line] = o.r1;
        y[(lane + 128) * N + line] = o.r2;
        y[(lane + 192) * N + line] = o.r3;
        grid.sync();

        // ---- row phase: x2 = prox(y + q) on row `line`; q = v - x2; acc = max|y - x2| ----
        Dist w, o2 = {0.f, 0.f, 0.f, 0.f};
        const float* yr = y + line * N;
        w.r0 = yr[lane      ] + q.r0;
        w.r1 = yr[lane +  64] + q.r1;
        w.r2 = yr[lane + 128] + q.r2;
        w.r3 = yr[lane + 192] + q.r3;
        tv1d_scan(w, o2, lane);
        float d0 = (w.r0 - q.r0) - o2.r0;   // y - x2 (old q)
        float d1 = (w.r1 - q.r1) - o2.r1;
        float d2 = (w.r2 - q.r2) - o2.r2;
        float d3 = (w.r3 - q.r3) - o2.r3;
        q.r0 = w.r0 - o2.r0;  q.r1 = w.r1 - o2.r1;
        q.r2 = w.r2 - o2.r2;  q.r3 = w.r3 - o2.r3;
        float* xr = xw + line * N;
        xr[lane      ] = o2.r0;
        xr[lane +  64] = o2.r1;
        xr[lane + 128] = o2.r2;
        xr[lane + 192] = o2.r3;

        float am = fmaxf(fmaxf(fabsf(d0), fabsf(d1)), fmaxf(fabsf(d2), fabsf(d3)));
        #pragma unroll
        for (int off = 32; off > 0; off >>= 1)
            am = fmaxf(am, __shfl_xor(am, off));
        if (lane == 0) atomicMax(&acc[it], __float_as_uint(am));   // am >= 0: uint order == float order
        grid.sync();

        unsigned a = __hip_atomic_load(&acc[it], __ATOMIC_RELAXED, __HIP_MEMORY_SCOPE_AGENT);
        if (__uint_as_float(a) < TOL) break;   // uniform across grid
    }
}

extern "C" void kernel_launch(void* const* d_in, const int* in_sizes, int n_in,
                              void* d_out, int out_size, void* d_ws, size_t ws_size,
                              hipStream_t stream) {
    const float* X = (const float*)d_in[0];
    float* xw = (float*)d_out;
    float* y = (float*)d_ws;
    unsigned* acc = (unsigned*)((char*)d_ws + (size_t)N * N * sizeof(float));
    void* args[] = { (void*)&X, (void*)&xw, (void*)&y, (void*)&acc };
    hipLaunchCooperativeKernel((void*)tv2d_coop, dim3(NB), dim3(NT), args, 0, stream);
}

// Round 3
// 882.329 us; speedup vs baseline: 3.4012x; 1.3278x over previous
//
#include <hip/hip_runtime.h>
#include <hip/hip_cooperative_groups.h>

#define N 256
#define NLINE 4               // lines (waves) per block
#define NB (N / NLINE)        // 64 blocks
#define NT (NLINE * 64)       // 256 threads
#define LAM 0.05f             // step = ALPHA/2
#define MAXIT 35
#define TOL 0.01f

namespace cg = cooperative_groups;

// broadcast-read one lane's register (lane index is wave-uniform -> v_readlane)
__device__ __forceinline__ float rlane(float v, int lane) {
    return __int_as_float(__builtin_amdgcn_readlane(__float_as_int(v), lane));
}

// a 256-float line distributed over the wave: element k lives in lane (k&63), reg (k>>6)
struct Dist { float r0, r1, r2, r3; };

// branchless fetch: 4 independent readlanes + 2 uniform selects (no s_cbranch)
__device__ __forceinline__ float dfetch(const Dist& d, int k) {
    const int lane = k & 63;
    const int sel = k >> 6;
    float a = rlane(d.r0, lane);
    float b = rlane(d.r1, lane);
    float c = rlane(d.r2, lane);
    float e = rlane(d.r3, lane);
    float ab = (sel & 1) ? b : a;
    float ce = (sel & 1) ? e : c;
    return (sel & 2) ? ce : ab;
}

// O(1) segment flush: o[j] = val for j in [lo, hi] — 4 regs x (2 cmp + and + cndmask)
__device__ __forceinline__ void flushseg(Dist& o, int lo, int hi, float val, int lane) {
    const int i0 = lane, i1 = lane + 64, i2 = lane + 128, i3 = lane + 192;
    o.r0 = (i0 >= lo && i0 <= hi) ? val : o.r0;
    o.r1 = (i1 >= lo && i1 <= hi) ? val : o.r1;
    o.r2 = (i2 >= lo && i2 <= hi) ? val : o.r2;
    o.r3 = (i3 >= lo && i3 <= hi) ? val : o.r3;
}

// Condat's exact 1D TV prox; wave-uniform control flow, register-resident line,
// O(1) segment flushes, predicated slope updates, rcp instead of div on hot path.
__device__ void tv1d_scan(const Dist& v, Dist& o, const int lane)
{
    const float lam = LAM, mlam = -LAM, twolam = 2.0f * LAM;
    int k = 0, k0 = 0, km = 0, kp = 0;
    float umin = lam, umax = mlam;
    const float v0 = rlane(v.r0, 0);
    float vmin = v0 - lam, vmax = v0 + lam;
    float flen = 1.0f;                 // = k - k0 + 1
    int guard = 0;
    for (;;) {
        if (++guard > 5000) return;    // provably terminates; belt+suspenders
        while (k == N - 1) {
            if (umin < 0.0f) {                       // negative jump at right boundary
                flushseg(o, k0, km, vmin, lane);
                k0 = km + 1;
                if (k0 > N - 1) return;
                km = k = k0;
                vmin = dfetch(v, k0);
                umin = lam;
                umax = vmin + lam - vmax;
                flen = 1.0f;
            } else if (umax > 0.0f) {                // positive jump at right boundary
                flushseg(o, k0, kp, vmax, lane);
                k0 = kp + 1;
                if (k0 > N - 1) return;
                kp = k = k0;
                vmax = dfetch(v, k0);
                umax = mlam;
                umin = vmax - lam - vmin;
                flen = 1.0f;
            } else {                                 // done: flush last segment
                vmin += umin / flen;
                flushseg(o, k0, k, vmin, lane);
                return;
            }
        }
        const float vn = dfetch(v, k + 1);
        umin += vn - vmin;
        umax += vn - vmax;
        if (umin < mlam) {                           // negative jump
            flushseg(o, k0, km, vmin, lane);
            k0 = km + 1;
            kp = km = k = k0;
            vmin = dfetch(v, k0);
            vmax = vmin + twolam;
            umin = lam; umax = mlam;
            flen = 1.0f;
        } else if (umax > lam) {                     // positive jump
            flushseg(o, k0, kp, vmax, lane);
            k0 = kp + 1;
            kp = km = k = k0;
            vmax = dfetch(v, k0);
            vmin = vmax - twolam;
            umin = lam; umax = mlam;
            flen = 1.0f;
        } else {                                     // no jump (hot path, predicated)
            k++;
            flen += 1.0f;
            const float r = __builtin_amdgcn_rcpf(flen);
            const bool cmin = (umin >= lam);
            const bool cmax = (umax <= mlam);
            vmin = cmin ? fmaf(umin - lam, r, vmin) : vmin;
            km   = cmin ? k : km;
            umin = cmin ? lam : umin;
            vmax = cmax ? fmaf(umax + lam, r, vmax) : vmax;
            kp   = cmax ? k : kp;
            umax = cmax ? mlam : umax;
        }
    }
}

// Douglas-Rachford TV2D: wave w of block b owns column (4b+w) in phase 1 and row (4b+w)
// in phase 2. p (column-local) and q (row-local) persist in registers across iterations.
__global__ __launch_bounds__(NT) void tv2d_coop(const float* __restrict__ X,
                                                float* __restrict__ xw,   // = d_out, holds x
                                                float* __restrict__ y,
                                                unsigned* __restrict__ acc)
{
    cg::grid_group grid = cg::this_grid();
    const int t = threadIdx.x;
    const int lane = t & 63;
    const int wave = t >> 6;
    const int line = blockIdx.x * NLINE + wave;

    if (blockIdx.x == 0 && t < MAXIT) acc[t] = 0u;   // ordered before use by first grid.sync

    Dist p = {0.f, 0.f, 0.f, 0.f};
    Dist q = {0.f, 0.f, 0.f, 0.f};

    for (int it = 0; it < MAXIT; ++it) {
        // ---- column phase: y = prox(x + p) on column `line`; p = v - y ----
        const float* xs = (it == 0) ? X : xw;
        Dist v, o;
        v.r0 = xs[(lane      ) * N + line] + p.r0;
        v.r1 = xs[(lane +  64) * N + line] + p.r1;
        v.r2 = xs[(lane + 128) * N + line] + p.r2;
        v.r3 = xs[(lane + 192) * N + line] + p.r3;
        tv1d_scan(v, o, lane);
        p.r0 = v.r0 - o.r0;  p.r1 = v.r1 - o.r1;
        p.r2 = v.r2 - o.r2;  p.r3 = v.r3 - o.r3;
        y[(lane      ) * N + line] = o.r0;
        y[(lane +  64) * N + line] = o.r1;
        y[(lane + 128) * N + line] = o.r2;
        y[(lane + 192) * N + line] = o.r3;
        grid.sync();

        // ---- row phase: x2 = prox(y + q) on row `line`; q = v - x2; acc = max|y - x2| ----
        Dist w, o2;
        const float* yr = y + line * N;
        w.r0 = yr[lane      ] + q.r0;
        w.r1 = yr[lane +  64] + q.r1;
        w.r2 = yr[lane + 128] + q.r2;
        w.r3 = yr[lane + 192] + q.r3;
        tv1d_scan(w, o2, lane);
        float d0 = (w.r0 - q.r0) - o2.r0;   // y - x2 (uses old q)
        float d1 = (w.r1 - q.r1) - o2.r1;
        float d2 = (w.r2 - q.r2) - o2.r2;
        float d3 = (w.r3 - q.r3) - o2.r3;
        q.r0 = w.r0 - o2.r0;  q.r1 = w.r1 - o2.r1;
        q.r2 = w.r2 - o2.r2;  q.r3 = w.r3 - o2.r3;
        float* xr = xw + line * N;
        xr[lane      ] = o2.r0;
        xr[lane +  64] = o2.r1;
        xr[lane + 128] = o2.r2;
        xr[lane + 192] = o2.r3;

        float am = fmaxf(fmaxf(fabsf(d0), fabsf(d1)), fmaxf(fabsf(d2), fabsf(d3)));
        #pragma unroll
        for (int off = 32; off > 0; off >>= 1)
            am = fmaxf(am, __shfl_xor(am, off));
        if (lane == 0) atomicMax(&acc[it], __float_as_uint(am));   // am >= 0: uint order == float order
        grid.sync();

        unsigned a = __hip_atomic_load(&acc[it], __ATOMIC_RELAXED, __HIP_MEMORY_SCOPE_AGENT);
        if (__uint_as_float(a) < TOL) break;   // uniform across grid
    }
}

extern "C" void kernel_launch(void* const* d_in, const int* in_sizes, int n_in,
                              void* d_out, int out_size, void* d_ws, size_t ws_size,
                              hipStream_t stream) {
    const float* X = (const float*)d_in[0];
    float* xw = (float*)d_out;
    float* y = (float*)d_ws;
    unsigned* acc = (unsigned*)((char*)d_ws + (size_t)N * N * sizeof(float));
    void* args[] = { (void*)&X, (void*)&xw, (void*)&y, (void*)&acc };
    hipLaunchCooperativeKernel((void*)tv2d_coop, dim3(NB), dim3(NT), args, 0, stream);
}